// Round 2
// 2793.788 us; speedup vs baseline: 1.1542x; 1.1542x over previous
//
#include <hip/hip_runtime.h>
#include <stdint.h>
#include <stddef.h>

// ---------------------------------------------------------------------------
// LSTM (B=64, T=1024, I=256, H=512) + attention pooling on MI355X (gfx950).
//   k_lstm v6: 128 blocks x 512 thr; 8 chains x 16 blocks (8 batches x 32
//   units per block). v4 skeleton unchanged; chain sync made XCD-local:
//   Under round-robin dispatch, bid%8 = XCD, so chain c = {c, c+8, ...,
//   c+120} shares one XCD. Each block publishes HW_REG_XCC_ID (numeric
//   s_getreg builtin) into its chain's 16 slots; each chain INDEPENDENTLY
//   checks "all 16 equal" -> decision uniform within chain by construction
//   (derived from the same written-once values; no cross-chain coupling, no
//   guard divergence). fast -> all per-step sync (h store/drain/flag/poll/
//   gather) at SE/L2 scope (sc0 only: L1 bypass, coherent via the shared
//   per-XCD L2, ~150-300cyc). mismatch -> exact v4 device-scope semantics.
//   v5 post-mortem: global 64-slot balance handshake could diverge (guard
//   trip) -> mixed scopes -> livelock; symbolic hwreg() asm also a compat
//   risk. Both removed.
// ---------------------------------------------------------------------------

typedef _Float16 f16_t;
typedef _Float16 half8 __attribute__((ext_vector_type(8)));
typedef float f32x4 __attribute__((ext_vector_type(4)));

#define MFMA16(a, b, c) __builtin_amdgcn_mfma_f32_16x16x32_f16((a), (b), (c), 0, 0, 0)

static constexpr int BATCH = 64;
static constexpr int TLEN = 1024;
static constexpr int IDIM = 256;
static constexpr int HDIM = 512;

__device__ __forceinline__ float sigf(float x) { return 1.f / (1.f + __expf(-x)); }
__device__ __forceinline__ float tanh_fast(float x) {
  float e = __expf(2.f * fabsf(x));
  float t = 1.f - 2.f / (e + 1.f);
  return copysignf(t, x);
}
__device__ __forceinline__ half8 load_cvt8(const float* p) {
  f32x4 a = *(const f32x4*)p;
  f32x4 b = *(const f32x4*)(p + 4);
  half8 r;
#pragma unroll
  for (int j = 0; j < 4; ++j) { r[j] = (f16_t)a[j]; r[4 + j] = (f16_t)b[j]; }
  return r;
}

// --- coherence helpers: llc=true -> system scope (sc0 sc1, cross-XCD, v4);
//     llc=false -> SE scope (sc0: L1-bypass, XCD L2 is the coherence point) --
__device__ __forceinline__ unsigned ld_flag(const unsigned* p, bool llc) {
  unsigned v;
  if (llc)
    asm volatile("global_load_dword %0, %1, off sc0 sc1\n\ts_waitcnt vmcnt(0)"
                 : "=&v"(v) : "v"(p) : "memory");
  else
    asm volatile("global_load_dword %0, %1, off sc0\n\ts_waitcnt vmcnt(0)"
                 : "=&v"(v) : "v"(p) : "memory");
  return v;
}
__device__ __forceinline__ f32x4 ld16_coh(const f16_t* p, bool llc) {
  f32x4 v;
  if (llc)
    asm volatile("global_load_dwordx4 %0, %1, off sc0 sc1\n\ts_waitcnt vmcnt(0)"
                 : "=&v"(v) : "v"(p) : "memory");
  else
    asm volatile("global_load_dwordx4 %0, %1, off sc0\n\ts_waitcnt vmcnt(0)"
                 : "=&v"(v) : "v"(p) : "memory");
  return v;
}
__device__ __forceinline__ void st16_coh(f16_t* p, f32x4 v, bool llc) {
  if (llc)
    asm volatile("global_store_dwordx4 %0, %1, off sc0 sc1" :: "v"(p), "v"(v) : "memory");
  else
    asm volatile("global_store_dwordx4 %0, %1, off sc0" :: "v"(p), "v"(v) : "memory");
}
__device__ __forceinline__ void st_flag(unsigned* p, unsigned v, bool llc) {
  if (llc)
    asm volatile("global_store_dword %0, %1, off sc0 sc1" :: "v"(p), "v"(v) : "memory");
  else
    asm volatile("global_store_dword %0, %1, off sc0" :: "v"(p), "v"(v) : "memory");
}

// ---------------------------------------------------------------------------
__global__ __launch_bounds__(256) void k_prep_x(const float* __restrict__ x,
                                                f16_t* __restrict__ xT) {
  __shared__ f16_t sx[64][IDIM + 8];
  const int t = blockIdx.x;
  const int tid = threadIdx.x;
#pragma unroll 4
  for (int b = 0; b < 64; ++b)
    sx[b][tid] = (f16_t)x[((size_t)b * TLEN + t) * IDIM + tid];
  __syncthreads();
#pragma unroll
  for (int it = 0; it < 8; ++it) {
    const int c = it * 256 + tid;      // c = kk4*64 + b
    const int b = c & 63, kk4 = c >> 6;
    half8 v = *(const half8*)&sx[b][kk4 * 8];
    *(half8*)(xT + (((size_t)t * 32 + kk4) * 64 + b) * 8) = v;
  }
}

__global__ __launch_bounds__(256) void k_prep_w(const float* __restrict__ Wa,
                                                f16_t* __restrict__ WaT) {
  const int id = blockIdx.x * 256 + threadIdx.x;   // 0..32767
  const int n = id & 511, kk4 = id >> 9;
  half8 v = load_cvt8(&Wa[(size_t)n * HDIM + kk4 * 8]);
  *(half8*)(WaT + ((size_t)kk4 * HDIM + n) * 8) = v;
}

// ---------------------------------------------------------------------------
// Recurrence. Role (bg,ug) static: bg = bid&7 (chain), ug = bid>>3.
// Batches bg*8..+7, units ug*32..+31. Wave w: units u0=ug*32+w*4..+3.
// MFMA M rows [unit][gate] as in v4; N lanes col 0..15 carry batch (col&7)
// (cols 8..15 duplicate, discarded). bar layout (dwords):
//   [0..127]   8 chains x 16 flag dwords (64B line each)
//   [128..255] 8 chains x 16 XCC-id slots (xcc+1 per member block)
// ---------------------------------------------------------------------------
__global__ __launch_bounds__(512, 2) void k_lstm(
    const float* __restrict__ Whh, const float* __restrict__ Wih,
    const float* __restrict__ bih, const float* __restrict__ bhh,
    const f16_t* __restrict__ xT, f16_t* __restrict__ hs,
    unsigned int* __restrict__ bar) {
  const int tid = threadIdx.x;
  const int w = tid >> 6;                  // wave 0..7
  const int L = tid & 63;
  const int q = L >> 4, col = L & 15;
  const int bid = blockIdx.x;
  const int bg = bid & 7;                  // chain (== XCD under round-robin)
  const int ug = bid >> 3;                 // 0..15 unit group / chain rank

  // ---- per-chain placement check: publish XCC id, all-equal -> L2 scope ---
  const unsigned xcc = ((unsigned)__builtin_amdgcn_s_getreg((3 << 11) | 20)) & 0xfu;
  unsigned* slots = bar + 128 + bg * 16;
  if (tid == 0) {
    unsigned pv = xcc + 1u;
    asm volatile("global_store_dword %0, %1, off sc0 sc1\n\ts_waitcnt vmcnt(0)"
                 :: "v"(slots + ug), "v"(pv) : "memory");
  }
  unsigned slotv;
  {
    const unsigned* sp = slots + (L & 15); // lane L watches chain-rank L&15
    for (;;) {                             // no guard: 128 blocks co-resident
      slotv = ld_flag(sp, true);
      if (__ballot((L < 16) ? (slotv != 0u) : true) == ~0ull) break;
      __builtin_amdgcn_s_sleep(4);
    }
  }
  const unsigned v0 = __shfl(slotv, 0);    // rank-0 member's xcc+1
  const bool fast =
      (__ballot((L < 16) ? (slotv == v0) : true) == ~0ull);
  const bool llc = !fast;

  const int u0 = ug * 32 + w * 4;
  const int b8 = col & 7;                  // chain-local batch
  const int bglob = bg * 8 + b8;           // global batch
  const int myu = u0 + q;
  unsigned int* chainflags = bar + (size_t)bg * 16;   // 64B line, 16 dwords

  __shared__ __align__(16) f16_t hin[8][520];   // h(t-1): 1040B stride
  __shared__ __align__(16) f16_t hout[8][40];   // block's h(t) chunk

  // Persistent A-fragments: A[m=col][k=q*8+j]; m = unit_local*4 + gate.
  const int arow = (col & 3) * HDIM + u0 + (col >> 2);
  half8 wAh[16], wAx[8];
#pragma unroll
  for (int kk = 0; kk < 16; ++kk)
    wAh[kk] = load_cvt8(&Whh[(size_t)arow * HDIM + kk * 32 + q * 8]);
#pragma unroll
  for (int kk = 0; kk < 8; ++kk)
    wAx[kk] = load_cvt8(&Wih[(size_t)arow * IDIM + kk * 32 + q * 8]);

  float pb[4];
#pragma unroll
  for (int r = 0; r < 4; ++r) pb[r] = bih[r * HDIM + myu] + bhh[r * HDIM + myu];

  auto xgemm = [&](int t) {
    f32x4 a = {0.f, 0.f, 0.f, 0.f};
#pragma unroll
    for (int kk = 0; kk < 8; ++kk) {
      half8 bf = *(const half8*)(xT +
          (((size_t)(t - 1) * 32 + kk * 4 + q) * 64 + bglob) * 8);
      a = MFMA16(wAx[kk], bf, a);
    }
    return a;
  };

  float c = 0.f;
  f32x4 xacc = xgemm(1);
  for (int t = 1; t <= TLEN; ++t) {
    // ---- wait for all 16 producer flags >= t-1 (each wave independently) --
    if (t > 1) {
      const unsigned tgt = (unsigned)(t - 1);
      const unsigned* fl = chainflags + (L & 15);
      int guard = 0;
      for (;;) {
        unsigned v = ld_flag(fl, llc);
        const bool ok = (L < 16) ? (v >= tgt) : true;
        if (__ballot(ok) == ~0ull) break;
        __builtin_amdgcn_s_sleep(1);
        if (++guard > (1 << 25)) break;    // fail loud, not hung
      }
    }

    // ---- gather h(t-1): wave w loads full row of batch bg*8+w -> LDS ----
    {
      const f16_t* src = hs + ((size_t)(t - 1) * BATCH + bg * 8 + w) * HDIM
                         + L * 8;          // 64 lanes x 16B = 1KB row
      f32x4 v = ld16_coh(src, llc);
      *(f32x4*)&hin[w][L * 8] = v;
    }
    __syncthreads();                       // hin complete

    // ---- MFMA: B-frags broadcast-read from LDS, dual accumulators ----
    f32x4 a0 = xacc, a1 = {0.f, 0.f, 0.f, 0.f};
#pragma unroll
    for (int kk = 0; kk < 16; kk += 2) {
      half8 b0 = *(const half8*)&hin[b8][kk * 32 + q * 8];
      half8 b1 = *(const half8*)&hin[b8][(kk + 1) * 32 + q * 8];
      a0 = MFMA16(wAh[kk], b0, a0);
      a1 = MFMA16(wAh[kk + 1], b1, a1);
    }
    const f32x4 acc = a0 + a1;

    const float ig = sigf(acc[0] + pb[0]);
    const float fg = sigf(acc[1] + pb[1]);
    const float gg = tanh_fast(acc[2] + pb[2]);
    const float og = sigf(acc[3] + pb[3]);
    c = fg * c + ig * gg;
    if (col < 8) hout[col][w * 4 + q] = (f16_t)(og * tanh_fast(c));

    __syncthreads();                       // hout ready, hin consumed

    // ---- wave 0: 8x64B coalesced stores + drain + flag=t ----
    if (w == 0) {
      if (L < 32) {
        const int sb = L >> 2, q4 = L & 3;
        f32x4 v = *(const f32x4*)&hout[sb][q4 * 8];
        f16_t* dst = hs + ((size_t)t * BATCH + bg * 8 + sb) * HDIM
                     + ug * 32 + q4 * 8;
        st16_coh(dst, v, llc);
      }
      asm volatile("s_waitcnt vmcnt(0)" ::: "memory");
      if (L == 0) st_flag(chainflags + ug, (unsigned)t, llc);
    }

    // x-projection for the NEXT step: overlaps other blocks' compute
    if (t < TLEN) xacc = xgemm(t + 1);
  }
}

// ---------------------------------------------------------------------------
__global__ __launch_bounds__(256) void k_attn(
    const f16_t* __restrict__ hse, const f16_t* __restrict__ WaT,
    const float* __restrict__ battn, f16_t* __restrict__ E) {
  const int w = threadIdx.x >> 6;
  const int L = threadIdx.x & 63;
  const int q = L >> 4, col = L & 15;
  const int m0 = blockIdx.x * 64 + w * 16;   // r rows (r = t*64+b)
  const int n0 = blockIdx.y * 64;            // h cols

  f32x4 acc[4];
#pragma unroll
  for (int nt = 0; nt < 4; ++nt) acc[nt] = {0.f, 0.f, 0.f, 0.f};

#pragma unroll 4
  for (int kk = 0; kk < 16; ++kk) {          // K = 512
    half8 af = *(const half8*)(hse + (size_t)(m0 + col) * HDIM + kk * 32 + q * 8);
#pragma unroll
    for (int nt = 0; nt < 4; ++nt) {
      half8 bf = *(const half8*)(WaT +
          ((size_t)(kk * 4 + q) * HDIM + n0 + nt * 16 + col) * 8);
      acc[nt] = MFMA16(af, bf, acc[nt]);
    }
  }
#pragma unroll
  for (int nt = 0; nt < 4; ++nt) {
    const int h = n0 + nt * 16 + col;
    const float bias = battn[h];
#pragma unroll
    for (int r = 0; r < 4; ++r) {
      const int m = m0 + q * 4 + r;
      E[(size_t)m * HDIM + h] = (f16_t)__expf(tanh_fast(acc[nt][r] + bias));
    }
  }
}

__global__ __launch_bounds__(256) void k_pool(
    const f16_t* __restrict__ E, const f16_t* __restrict__ hse,
    float* __restrict__ pnum, float* __restrict__ pden) {
  const int b = blockIdx.x;
  const int hc = blockIdx.y;
  const int tc = blockIdx.z;
  const int h = hc * 256 + threadIdx.x;
  float num = 0.f, den = 0.f;
#pragma unroll 4
  for (int tt = 0; tt < 256; ++tt) {
    const int t = tc * 256 + tt;
    const size_t idx = ((size_t)t * BATCH + b) * HDIM + h;
    const float e = (float)E[idx];
    const float hv = (float)hse[idx];
    den += e;
    num += e * hv;
  }
  const size_t pi = ((size_t)tc * BATCH + b) * HDIM + h;
  pnum[pi] = num;
  pden[pi] = den;
}

__global__ __launch_bounds__(256) void k_final(
    const float* __restrict__ pnum, const float* __restrict__ pden,
    float* __restrict__ out) {
  const int i = blockIdx.x * 256 + threadIdx.x;   // b*512+h
  float n = 0.f, d = 0.f;
#pragma unroll
  for (int z = 0; z < 4; ++z) {
    n += pnum[(size_t)z * 32768 + i];
    d += pden[(size_t)z * 32768 + i];
  }
  out[i] = n / d;
}

// ---------------------------------------------------------------------------
extern "C" void kernel_launch(void* const* d_in, const int* in_sizes, int n_in,
                              void* d_out, int out_size, void* d_ws, size_t ws_size,
                              hipStream_t stream) {
  const float* x   = (const float*)d_in[0];
  const float* Wih = (const float*)d_in[1];
  const float* Whh = (const float*)d_in[2];
  const float* bih = (const float*)d_in[3];
  const float* bhh = (const float*)d_in[4];
  const float* Wat = (const float*)d_in[5];
  const float* bat = (const float*)d_in[6];
  float* out = (float*)d_out;

  char* ws = (char*)d_ws;
  const size_t REGA_BYTES = (size_t)64 * 1024 * 1024;                        // xT then E
  const size_t HS_BYTES = (size_t)(TLEN + 1) * BATCH * HDIM * sizeof(f16_t); // 67.2MB
  const size_t WAT_BYTES = (size_t)64 * HDIM * 8 * sizeof(f16_t);            // 512KB
  const size_t P_BYTES = (size_t)4 * BATCH * HDIM * sizeof(float);           // 512KB

  f16_t* xT = (f16_t*)ws;
  f16_t* E  = (f16_t*)ws;
  f16_t* hs = (f16_t*)(ws + REGA_BYTES);
  f16_t* WaT = (f16_t*)(ws + REGA_BYTES + HS_BYTES);
  float* pnum = (float*)(ws + REGA_BYTES + HS_BYTES + WAT_BYTES);
  float* pden = (float*)(ws + REGA_BYTES + HS_BYTES + WAT_BYTES + P_BYTES);
  unsigned int* bar = (unsigned int*)(ws + REGA_BYTES + HS_BYTES + WAT_BYTES + 2 * P_BYTES);

  hipMemsetAsync(hs, 0, (size_t)BATCH * HDIM * sizeof(f16_t), stream);
  hipMemsetAsync(bar, 0, 1024, stream);   // 8x16 flags + 8x16 XCC slots

  k_prep_x<<<dim3(TLEN), 256, 0, stream>>>(x, xT);
  k_prep_w<<<dim3(128), 256, 0, stream>>>(Wat, WaT);
  k_lstm<<<dim3(128), 512, 0, stream>>>(Whh, Wih, bih, bhh, xT, hs, bar);

  const f16_t* hse = hs + (size_t)BATCH * HDIM;   // slab 1 == reference hs[0]
  k_attn<<<dim3(1024, 8), 256, 0, stream>>>(hse, WaT, bat, E);
  k_pool<<<dim3(64, 2, 4), 256, 0, stream>>>(E, hse, pnum, pden);
  k_final<<<dim3(128), 256, 0, stream>>>(pnum, pden, out);
}

// Round 4
// 2728.361 us; speedup vs baseline: 1.1818x; 1.0240x over previous
//
#include <hip/hip_runtime.h>
#include <stdint.h>
#include <stddef.h>

// ---------------------------------------------------------------------------
// LSTM (B=64, T=1024, I=256, H=512) + attention pooling on MI355X (gfx950).
//   k_lstm v8: 128 blocks x 512 thr; 8 chains x 16 blocks (8 batches x 32
//   units per block) -- v6's proven geometry and DEVICE-scope coherence.
//   KEY CHANGE vs v6/v7: sentinel-carrying h. hs slabs 1..1024 are pre-
//   poisoned with 0xFEFE per f16 (NaN). h = o*tanh(c) is finite => a stored
//   f16 can never equal the sentinel. Consumers gather h(t-1) directly and
//   retry only lanes still seeing sentinel: the readiness poll and the data
//   gather are the SAME load. Producers store h with NO drain and NO flag.
//   Per-step sync: 3 device-scope legs (drain, flag store+poll, gather) -> 1
//   (store -> IC -> detect-by-gather). Torn 16B reads show sentinel in some
//   u16 and are retried, so no store-atomicity assumption is needed.
//   v7 post-mortem: SE-scope (sc0-only) sync hung (v5 too; v6's fallback
//   passed) -- per-XCD L2 non-coherence + 128B-line false sharing between
//   adjacent chains' 64B flag lines is livelock-capable. Scope tricks
//   abandoned; leg-count reduced instead.
// ---------------------------------------------------------------------------

typedef _Float16 f16_t;
typedef _Float16 half8 __attribute__((ext_vector_type(8)));
typedef float f32x4 __attribute__((ext_vector_type(4)));

#define MFMA16(a, b, c) __builtin_amdgcn_mfma_f32_16x16x32_f16((a), (b), (c), 0, 0, 0)

static constexpr int BATCH = 64;
static constexpr int TLEN = 1024;
static constexpr int IDIM = 256;
static constexpr int HDIM = 512;

__device__ __forceinline__ float sigf(float x) { return 1.f / (1.f + __expf(-x)); }
__device__ __forceinline__ float tanh_fast(float x) {
  float e = __expf(2.f * fabsf(x));
  float t = 1.f - 2.f / (e + 1.f);
  return copysignf(t, x);
}
__device__ __forceinline__ half8 load_cvt8(const float* p) {
  f32x4 a = *(const f32x4*)p;
  f32x4 b = *(const f32x4*)(p + 4);
  half8 r;
#pragma unroll
  for (int j = 0; j < 4; ++j) { r[j] = (f16_t)a[j]; r[4 + j] = (f16_t)b[j]; }
  return r;
}

// device-scope (sc0 sc1) 16B load with completion wait: IC is the coherence
// point across XCDs -- the path v4/v6 validated.
__device__ __forceinline__ f32x4 ld16_llc(const f16_t* p) {
  f32x4 v;
  asm volatile("global_load_dwordx4 %0, %1, off sc0 sc1\n\ts_waitcnt vmcnt(0)"
               : "=&v"(v) : "v"(p) : "memory");
  return v;
}

// true iff none of the 8 f16 lanes equals the 0xFEFE sentinel
__device__ __forceinline__ bool clean16(const f32x4& v) {
  const unsigned* u = (const unsigned*)&v;
  bool ok = true;
#pragma unroll
  for (int i = 0; i < 4; ++i) {
    ok = ok && ((u[i] & 0xFFFFu) != 0xFEFEu);
    ok = ok && ((u[i] >> 16) != 0xFEFEu);
  }
  return ok;
}

// ---------------------------------------------------------------------------
__global__ __launch_bounds__(256) void k_prep_x(const float* __restrict__ x,
                                                f16_t* __restrict__ xT) {
  __shared__ f16_t sx[64][IDIM + 8];
  const int t = blockIdx.x;
  const int tid = threadIdx.x;
#pragma unroll 4
  for (int b = 0; b < 64; ++b)
    sx[b][tid] = (f16_t)x[((size_t)b * TLEN + t) * IDIM + tid];
  __syncthreads();
#pragma unroll
  for (int it = 0; it < 8; ++it) {
    const int c = it * 256 + tid;      // c = kk4*64 + b
    const int b = c & 63, kk4 = c >> 6;
    half8 v = *(const half8*)&sx[b][kk4 * 8];
    *(half8*)(xT + (((size_t)t * 32 + kk4) * 64 + b) * 8) = v;
  }
}

__global__ __launch_bounds__(256) void k_prep_w(const float* __restrict__ Wa,
                                                f16_t* __restrict__ WaT) {
  const int id = blockIdx.x * 256 + threadIdx.x;   // 0..32767
  const int n = id & 511, kk4 = id >> 9;
  half8 v = load_cvt8(&Wa[(size_t)n * HDIM + kk4 * 8]);
  *(half8*)(WaT + ((size_t)kk4 * HDIM + n) * 8) = v;
}

// ---------------------------------------------------------------------------
// Recurrence. Roles static: bg = bid&7 (chain), ug = bid>>3 (rank).
// Batches bg*8..+7, units ug*32..+31. Wave w: units u0=ug*32+w*4..+3.
// MFMA M rows [unit][gate]; N lanes col 0..15 carry batch (col&7) (cols
// 8..15 duplicate, discarded on store). No flags, no barrier words: h(t)
// stores into sentinel-poisoned hs are self-announcing.
// ---------------------------------------------------------------------------
__global__ __launch_bounds__(512, 2) void k_lstm(
    const float* __restrict__ Whh, const float* __restrict__ Wih,
    const float* __restrict__ bih, const float* __restrict__ bhh,
    const f16_t* __restrict__ xT, f16_t* __restrict__ hs) {
  const int tid = threadIdx.x;
  const int w = tid >> 6;                  // wave 0..7
  const int L = tid & 63;
  const int q = L >> 4, col = L & 15;
  const int bid = blockIdx.x;
  const int bg = bid & 7;                  // chain / batch group
  const int ug = bid >> 3;                 // 0..15 unit group

  const int u0 = ug * 32 + w * 4;
  const int b8 = col & 7;                  // chain-local batch
  const int bglob = bg * 8 + b8;           // global batch
  const int myu = u0 + q;

  __shared__ __align__(16) f16_t hin[8][520];   // h(t-1): 1040B stride
  __shared__ __align__(16) f16_t hout[8][40];   // block's h(t) chunk

  // Persistent A-fragments: A[m=col][k=q*8+j]; m = unit_local*4 + gate.
  const int arow = (col & 3) * HDIM + u0 + (col >> 2);
  half8 wAh[16], wAx[8];
#pragma unroll
  for (int kk = 0; kk < 16; ++kk)
    wAh[kk] = load_cvt8(&Whh[(size_t)arow * HDIM + kk * 32 + q * 8]);
#pragma unroll
  for (int kk = 0; kk < 8; ++kk)
    wAx[kk] = load_cvt8(&Wih[(size_t)arow * IDIM + kk * 32 + q * 8]);

  float pb[4];
#pragma unroll
  for (int r = 0; r < 4; ++r) pb[r] = bih[r * HDIM + myu] + bhh[r * HDIM + myu];

  auto xgemm = [&](int t) {
    f32x4 a = {0.f, 0.f, 0.f, 0.f};
#pragma unroll
    for (int kk = 0; kk < 8; ++kk) {
      half8 bf = *(const half8*)(xT +
          (((size_t)(t - 1) * 32 + kk * 4 + q) * 64 + bglob) * 8);
      a = MFMA16(wAx[kk], bf, a);
    }
    return a;
  };

  float c = 0.f;
  f32x4 xacc = xgemm(1);
  for (int t = 1; t <= TLEN; ++t) {
    // ---- gather h(t-1) with data-embedded readiness: wave w polls the full
    //      512-unit row of batch bg*8+w; only stale lanes re-fetch ----
    {
      const f16_t* src = hs + ((size_t)(t - 1) * BATCH + bg * 8 + w) * HDIM
                         + L * 8;          // 16B per lane, 1KB per wave
      f32x4 v = ld16_llc(src);
      int guard = 0;
      for (;;) {
        const bool ok = clean16(v);
        if (__ballot(ok) == ~0ull) break;
        if (!ok) v = ld16_llc(src);        // exec-masked retry
        if (++guard > (1 << 22)) break;    // fail loud, not hung
      }
      *(f32x4*)&hin[w][L * 8] = v;
    }
    __syncthreads();                       // hin complete

    // ---- MFMA: B-frags broadcast-read from LDS, dual accumulators ----
    f32x4 a0 = xacc, a1 = {0.f, 0.f, 0.f, 0.f};
#pragma unroll
    for (int kk = 0; kk < 16; kk += 2) {
      half8 b0 = *(const half8*)&hin[b8][kk * 32 + q * 8];
      half8 b1 = *(const half8*)&hin[b8][(kk + 1) * 32 + q * 8];
      a0 = MFMA16(wAh[kk], b0, a0);
      a1 = MFMA16(wAh[kk + 1], b1, a1);
    }
    const f32x4 acc = a0 + a1;

    const float ig = sigf(acc[0] + pb[0]);
    const float fg = sigf(acc[1] + pb[1]);
    const float gg = tanh_fast(acc[2] + pb[2]);
    const float og = sigf(acc[3] + pb[3]);
    c = fg * c + ig * gg;
    if (col < 8) hout[col][w * 4 + q] = (f16_t)(og * tanh_fast(c));

    __syncthreads();                       // hout ready, hin consumed

    // ---- wave 0: 8x64B coalesced stores; no drain, no flag ----
    if (w == 0 && L < 32) {
      const int sb = L >> 2, q4 = L & 3;
      f32x4 v = *(const f32x4*)&hout[sb][q4 * 8];
      f16_t* dst = hs + ((size_t)t * BATCH + bg * 8 + sb) * HDIM
                   + ug * 32 + q4 * 8;
      asm volatile("global_store_dwordx4 %0, %1, off sc0 sc1"
                   :: "v"(dst), "v"(v) : "memory");
    }

    // x-projection for the NEXT step: overlaps other blocks' compute
    if (t < TLEN) xacc = xgemm(t + 1);
  }
}

// ---------------------------------------------------------------------------
__global__ __launch_bounds__(256) void k_attn(
    const f16_t* __restrict__ hse, const f16_t* __restrict__ WaT,
    const float* __restrict__ battn, f16_t* __restrict__ E) {
  const int w = threadIdx.x >> 6;
  const int L = threadIdx.x & 63;
  const int q = L >> 4, col = L & 15;
  const int m0 = blockIdx.x * 64 + w * 16;   // r rows (r = t*64+b)
  const int n0 = blockIdx.y * 64;            // h cols

  f32x4 acc[4];
#pragma unroll
  for (int nt = 0; nt < 4; ++nt) acc[nt] = {0.f, 0.f, 0.f, 0.f};

#pragma unroll 4
  for (int kk = 0; kk < 16; ++kk) {          // K = 512
    half8 af = *(const half8*)(hse + (size_t)(m0 + col) * HDIM + kk * 32 + q * 8);
#pragma unroll
    for (int nt = 0; nt < 4; ++nt) {
      half8 bf = *(const half8*)(WaT +
          ((size_t)(kk * 4 + q) * HDIM + n0 + nt * 16 + col) * 8);
      acc[nt] = MFMA16(af, bf, acc[nt]);
    }
  }
#pragma unroll
  for (int nt = 0; nt < 4; ++nt) {
    const int h = n0 + nt * 16 + col;
    const float bias = battn[h];
#pragma unroll
    for (int r = 0; r < 4; ++r) {
      const int m = m0 + q * 4 + r;
      E[(size_t)m * HDIM + h] = (f16_t)__expf(tanh_fast(acc[nt][r] + bias));
    }
  }
}

__global__ __launch_bounds__(256) void k_pool(
    const f16_t* __restrict__ E, const f16_t* __restrict__ hse,
    float* __restrict__ pnum, float* __restrict__ pden) {
  const int b = blockIdx.x;
  const int hc = blockIdx.y;
  const int tc = blockIdx.z;
  const int h = hc * 256 + threadIdx.x;
  float num = 0.f, den = 0.f;
#pragma unroll 4
  for (int tt = 0; tt < 256; ++tt) {
    const int t = tc * 256 + tt;
    const size_t idx = ((size_t)t * BATCH + b) * HDIM + h;
    const float e = (float)E[idx];
    const float hv = (float)hse[idx];
    den += e;
    num += e * hv;
  }
  const size_t pi = ((size_t)tc * BATCH + b) * HDIM + h;
  pnum[pi] = num;
  pden[pi] = den;
}

__global__ __launch_bounds__(256) void k_final(
    const float* __restrict__ pnum, const float* __restrict__ pden,
    float* __restrict__ out) {
  const int i = blockIdx.x * 256 + threadIdx.x;   // b*512+h
  float n = 0.f, d = 0.f;
#pragma unroll
  for (int z = 0; z < 4; ++z) {
    n += pnum[(size_t)z * 32768 + i];
    d += pden[(size_t)z * 32768 + i];
  }
  out[i] = n / d;
}

// ---------------------------------------------------------------------------
extern "C" void kernel_launch(void* const* d_in, const int* in_sizes, int n_in,
                              void* d_out, int out_size, void* d_ws, size_t ws_size,
                              hipStream_t stream) {
  const float* x   = (const float*)d_in[0];
  const float* Wih = (const float*)d_in[1];
  const float* Whh = (const float*)d_in[2];
  const float* bih = (const float*)d_in[3];
  const float* bhh = (const float*)d_in[4];
  const float* Wat = (const float*)d_in[5];
  const float* bat = (const float*)d_in[6];
  float* out = (float*)d_out;

  char* ws = (char*)d_ws;
  const size_t REGA_BYTES = (size_t)64 * 1024 * 1024;                        // xT then E
  const size_t HS_BYTES = (size_t)(TLEN + 1) * BATCH * HDIM * sizeof(f16_t); // 67.2MB
  const size_t WAT_BYTES = (size_t)64 * HDIM * 8 * sizeof(f16_t);            // 512KB
  const size_t P_BYTES = (size_t)4 * BATCH * HDIM * sizeof(float);           // 512KB

  f16_t* xT = (f16_t*)ws;
  f16_t* E  = (f16_t*)ws;
  f16_t* hs = (f16_t*)(ws + REGA_BYTES);
  f16_t* WaT = (f16_t*)(ws + REGA_BYTES + HS_BYTES);
  float* pnum = (float*)(ws + REGA_BYTES + HS_BYTES + WAT_BYTES);
  float* pden = (float*)(ws + REGA_BYTES + HS_BYTES + WAT_BYTES + P_BYTES);

  const size_t SLAB = (size_t)BATCH * HDIM * sizeof(f16_t);   // 64KB
  // slab 0 = h(0) = zeros; slabs 1..1024 = 0xFEFE sentinel (re-poison every
  // launch: the sentinel IS the readiness protocol).
  hipMemsetAsync(hs, 0, SLAB, stream);
  hipMemsetAsync((char*)hs + SLAB, 0xFE, (size_t)TLEN * SLAB, stream);

  k_prep_x<<<dim3(TLEN), 256, 0, stream>>>(x, xT);
  k_prep_w<<<dim3(128), 256, 0, stream>>>(Wat, WaT);
  k_lstm<<<dim3(128), 512, 0, stream>>>(Whh, Wih, bih, bhh, xT, hs);

  const f16_t* hse = hs + (size_t)BATCH * HDIM;   // slab 1 == reference hs[0]
  k_attn<<<dim3(1024, 8), 256, 0, stream>>>(hse, WaT, bat, E);
  k_pool<<<dim3(64, 2, 4), 256, 0, stream>>>(E, hse, pnum, pden);
  k_final<<<dim3(128), 256, 0, stream>>>(pnum, pden, out);
}